// Round 9
// baseline (862.886 us; speedup 1.0000x reference)
//
#include <hip/hip_runtime.h>
#include <hip/hip_bf16.h>
#include <stdint.h>

#define PS 56
#define S_ 3136
#define DIM 128
#define NTOK 200704   // 64 * 3136

typedef __attribute__((ext_vector_type(8))) short short8;
typedef __attribute__((ext_vector_type(4))) float f32x4;

__device__ __forceinline__ uint32_t bfpack(float a, float b){
  uint32_t ua = __float_as_uint(a); ua = (ua + 0x7fffu + ((ua >> 16) & 1u)) >> 16;
  uint32_t ub = __float_as_uint(b); ub = (ub + 0x7fffu + ((ub >> 16) & 1u)) & 0xffff0000u;
  return ua | ub;
}
__device__ __forceinline__ uint16_t bf16of(float a){
  uint32_t ua = __float_as_uint(a);
  return (uint16_t)((ua + 0x7fffu + ((ua >> 16) & 1u)) >> 16);
}
// pad-row redirect: rows 49..63 are garbage-tolerant (feed only discarded outputs);
// funnel them into one sacrificial row so the LDS tile shrinks 64 -> 50 rows.
__device__ __forceinline__ int rr(int row){ return row > 48 ? 49 : row; }

__device__ __forceinline__ int win_map(int r, int shift) {
  int b = r / S_;
  int rem = r - b * S_;
  int w = rem / 49;
  int p = rem - w * 49;
  int i = p / 7, j = p - i * 7;
  int wr = w >> 3, wc = w & 7;
  int row = wr * 7 + i + shift; if (row >= PS) row -= PS;
  int col = wc * 7 + j + shift; if (col >= PS) col -= PS;
  return b * S_ + row * PS + col;
}

// ===== LN fused to bf16 (standalone, used once for ln1) =====
__global__ __launch_bounds__(256) void ln_k(const float* __restrict__ X,
                                            const float* __restrict__ g,
                                            const float* __restrict__ b,
                                            uint16_t* __restrict__ O) {
  int t = blockIdx.x * 4 + (threadIdx.x >> 6);
  int lane = threadIdx.x & 63;
  float2 v = *(const float2*)(X + (size_t)t * DIM + lane * 2);
  float s = v.x + v.y, sq = v.x * v.x + v.y * v.y;
  #pragma unroll
  for (int o = 32; o; o >>= 1) { s += __shfl_xor(s, o); sq += __shfl_xor(sq, o); }
  float mu = s * (1.0f / 128.0f);
  float rs = rsqrtf(sq * (1.0f / 128.0f) - mu * mu + 1e-5f);
  float2 gg = *(const float2*)(g + lane * 2);
  float2 bb = *(const float2*)(b + lane * 2);
  float a = (v.x - mu) * rs * gg.x + bb.x;
  float c = (v.y - mu) * rs * gg.y + bb.y;
  ((uint32_t*)O)[(size_t)t * 64 + lane] = bfpack(a, c);
}

// ===== one-shot weight conversion f32 -> bf16 =====
__global__ __launch_bounds__(256) void wconv_k(
    const float* __restrict__ w0, const float* __restrict__ w1,
    const float* __restrict__ w2, const float* __restrict__ w3,
    const float* __restrict__ w4, const float* __restrict__ w5,
    uint16_t* __restrict__ out) {
  int i = blockIdx.x * 256 + threadIdx.x;   // 0..163839
  float v;
  if      (i <  49152) v = w0[i];
  else if (i <  98304) v = w1[i -  49152];
  else if (i < 114688) v = w2[i -  98304];
  else if (i < 131072) v = w3[i - 114688];
  else if (i < 147456) v = w4[i - 131072];
  else                 v = w5[i - 147456];
  out[i] = bf16of(v);
}

// ================= bias precompute: biasT[h][k][q], mask baked =================
__global__ __launch_bounds__(256) void bias_k(const float* __restrict__ tbl, float* __restrict__ biasT) {
  int idx = blockIdx.x * 256 + threadIdx.x;   // (h<<12 | k<<6 | q)
  int h = idx >> 12;
  int k = (idx >> 6) & 63;
  int q = idx & 63;
  float v;
  if (k >= 49)      v = -1e30f;
  else if (q >= 49) v = 0.f;
  else {
    int yi = q / 7, xi = q - yi * 7;
    int yj = k / 7, xj = k - yj * 7;
    v = tbl[((yi - yj + 6) * 13 + (xi - xj + 6)) * 4 + h];
  }
  biasT[idx] = v;
}

// ===== attn4: fused qkv + QK^T + softmax + PV + Wo proj + residual + LN + MLP =====
// r8 structure with: (a) 50-row LDS tile via pad-row redirect -> 40,800 B -> 4 blocks/CU;
// (b) s_setprio(1) around pure-MFMA nests (T5).
constexpr int QKV_STR = 392;
constexpr int OS_STR  = 140;   // O / X_lds tile stride (bf16), aliases qs flat

template<int IN_SHIFT, int OUT_SHIFT, bool MLP_LN>
__global__ __launch_bounds__(256, 4) void attn4(const uint16_t* __restrict__ xbin,
                                             const uint16_t* __restrict__ Wqkv,
                                             const float* __restrict__ bqkv,
                                             const float* __restrict__ biasT,
                                             const uint16_t* __restrict__ Wo,
                                             const float* __restrict__ bo,
                                             const float* __restrict__ Rsrc,
                                             const uint16_t* __restrict__ Wm,
                                             const float* __restrict__ bm,
                                             const float* __restrict__ lnga,
                                             const float* __restrict__ lnba,
                                             const float* __restrict__ lngp,
                                             const float* __restrict__ lnbp,
                                             float* __restrict__ Xout,
                                             uint16_t* __restrict__ xbout)
{
  __shared__ __align__(16) uint16_t qs[50 * QKV_STR];   // rows 0..48 real, 49 pad-garbage
  __shared__ float lnred[50][4][2];
  const int tid = threadIdx.x;
  const int lane = tid & 63;
  const int h = tid >> 6;
  const int lanelow = lane & 15;
  const int quad = lane >> 4;
  const int base = blockIdx.x * 49;

  // ---- phase 0: qkv = xb@Wqkv^T + bqkv, straight into qs ----
  {
    short8 af[4][4];
    #pragma unroll
    for (int mt = 0; mt < 4; ++mt) {
      int tok = mt * 16 + lanelow; if (tok > 48) tok = 48;
      int src = win_map(base + tok, IN_SHIFT);
      const uint16_t* arow = xbin + (size_t)src * DIM;
      #pragma unroll
      for (int k0 = 0; k0 < 4; ++k0)
        af[mt][k0] = *(const short8*)(arow + k0 * 32 + quad * 8);
    }
    #pragma unroll
    for (int ntl = 0; ntl < 6; ++ntl) {
      int wrow = (ntl >> 1) * 128 + h * 32 + (ntl & 1) * 16 + lanelow;
      const uint16_t* wr_ = Wqkv + (size_t)wrow * DIM;
      short8 bfr[4];
      #pragma unroll
      for (int k0 = 0; k0 < 4; ++k0)
        bfr[k0] = *(const short8*)(wr_ + k0 * 32 + quad * 8);
      f32x4 a4[4];
      #pragma unroll
      for (int mt = 0; mt < 4; ++mt) a4[mt] = (f32x4){0.f, 0.f, 0.f, 0.f};
      __builtin_amdgcn_s_setprio(1);
      #pragma unroll
      for (int k0 = 0; k0 < 4; ++k0)
        #pragma unroll
        for (int mt = 0; mt < 4; ++mt)
          a4[mt] = __builtin_amdgcn_mfma_f32_16x16x32_bf16(af[mt][k0], bfr[k0], a4[mt], 0, 0, 0);
      __builtin_amdgcn_s_setprio(0);
      float bq = bqkv[wrow];
      #pragma unroll
      for (int mt = 0; mt < 4; ++mt)
        #pragma unroll
        for (int r = 0; r < 4; ++r)
          qs[rr(mt * 16 + quad * 4 + r) * QKV_STR + wrow] = bf16of(a4[mt][r] + bq);
    }
  }

  // ---- T14: prefetch residual + output-row indices ----
  const int n0 = h * 32 + lanelow, n1 = n0 + 16;
  int   orow_a[4][4];
  float r0a[4][4], r1a[4][4];
  #pragma unroll
  for (int qt = 0; qt < 4; ++qt)
    #pragma unroll
    for (int r = 0; r < 4; ++r) {
      int q = qt * 16 + quad * 4 + r;
      bool ok = (q < 49);
      int wrow = base + (ok ? q : 0);
      int orow = (OUT_SHIFT < 0) ? wrow : win_map(wrow, OUT_SHIFT);
      orow_a[qt][r] = orow;
      r0a[qt][r] = ok ? Rsrc[(size_t)orow * DIM + n0] : 0.f;
      r1a[qt][r] = ok ? Rsrc[(size_t)orow * DIM + n1] : 0.f;
    }

  // ---- S^T = K·Q^T (each wave reads only cols it wrote; barrier after reg loads) ----
  f32x4 sc[4][4];
  #pragma unroll
  for (int kt = 0; kt < 4; ++kt)
    #pragma unroll
    for (int qt = 0; qt < 4; ++qt) sc[kt][qt] = (f32x4){0.f, 0.f, 0.f, 0.f};
  {
    short8 kf[4], qf[4];
    const int kcol = 128 + h * 32 + quad * 8;
    const int qcol = h * 32 + quad * 8;
    #pragma unroll
    for (int t = 0; t < 4; ++t) {
      int tok = t * 16 + lanelow; if (tok > 48) tok = 48;
      kf[t] = *(const short8*)(qs + tok * QKV_STR + kcol);
      qf[t] = *(const short8*)(qs + tok * QKV_STR + qcol);
    }
    __syncthreads();   // all waves hold Q,K in regs; Q/K cols become dead -> P scratch
    __builtin_amdgcn_s_setprio(1);
    #pragma unroll
    for (int kt = 0; kt < 4; ++kt)
      #pragma unroll
      for (int qt = 0; qt < 4; ++qt)
        sc[kt][qt] = __builtin_amdgcn_mfma_f32_16x16x32_bf16(kf[kt], qf[qt], sc[kt][qt], 0, 0, 0);
    __builtin_amdgcn_s_setprio(0);
  }

  // ---- scale + bias + softmax over k ----
  const float* bh = biasT + h * 4096;
  #pragma unroll
  for (int kt = 0; kt < 4; ++kt)
    #pragma unroll
    for (int r = 0; r < 4; ++r) {
      const float* br = bh + (kt * 16 + quad * 4 + r) * 64 + lanelow;
      #pragma unroll
      for (int qt = 0; qt < 4; ++qt)
        sc[kt][qt][r] = fmaf(sc[kt][qt][r], 0.17677669529663689f, br[qt * 16]);
    }
  #pragma unroll
  for (int qt = 0; qt < 4; ++qt) {
    float m = sc[0][qt][0];
    #pragma unroll
    for (int kt = 0; kt < 4; ++kt)
      #pragma unroll
      for (int r = 0; r < 4; ++r) m = fmaxf(m, sc[kt][qt][r]);
    m = fmaxf(m, __shfl_xor(m, 16));
    m = fmaxf(m, __shfl_xor(m, 32));
    float s = 0.f;
    #pragma unroll
    for (int kt = 0; kt < 4; ++kt)
      #pragma unroll
      for (int r = 0; r < 4; ++r) {
        float e = __expf(sc[kt][qt][r] - m);
        sc[kt][qt][r] = e;
        s += e;
      }
    s += __shfl_xor(s, 16);
    s += __shfl_xor(s, 32);
    float inv = 1.0f / s;
    #pragma unroll
    for (int kt = 0; kt < 4; ++kt)
      #pragma unroll
      for (int r = 0; r < 4; ++r) sc[kt][qt][r] *= inv;
  }

  // ---- P (bf16) -> dead Q/K cols: P[q][k] at qs[rr(q)*STR + h*64 + k] ----
  uint16_t* pw = qs + h * 64;
  #pragma unroll
  for (int qt = 0; qt < 4; ++qt)
    #pragma unroll
    for (int kt = 0; kt < 4; ++kt) {
      uint2 pk;
      pk.x = bfpack(sc[kt][qt][0], sc[kt][qt][1]);
      pk.y = bfpack(sc[kt][qt][2], sc[kt][qt][3]);
      *(uint2*)(pw + rr(qt * 16 + lanelow) * QKV_STR + kt * 16 + quad * 4) = pk;
    }

  // ---- O = P·V ----
  f32x4 oc[4][2];
  #pragma unroll
  for (int qt = 0; qt < 4; ++qt)
    #pragma unroll
    for (int dt = 0; dt < 2; ++dt) oc[qt][dt] = (f32x4){0.f, 0.f, 0.f, 0.f};
  {
    short8 pf[4][2];
    #pragma unroll
    for (int qt = 0; qt < 4; ++qt)
      #pragma unroll
      for (int kp = 0; kp < 2; ++kp)
        pf[qt][kp] = *(const short8*)(pw + rr(qt * 16 + lanelow) * QKV_STR + kp * 32 + quad * 8);
    short8 vf[2][2];
    #pragma unroll
    for (int dt = 0; dt < 2; ++dt)
      #pragma unroll
      for (int kp = 0; kp < 2; ++kp) {
        short8 b;
        #pragma unroll
        for (int j = 0; j < 8; ++j) {
          int tok = kp * 32 + quad * 8 + j; if (tok > 48) tok = 48;
          b[j] = (short)qs[tok * QKV_STR + 256 + h * 32 + dt * 16 + lanelow];
        }
        vf[dt][kp] = b;
      }
    __builtin_amdgcn_s_setprio(1);
    #pragma unroll
    for (int qt = 0; qt < 4; ++qt)
      #pragma unroll
      for (int dt = 0; dt < 2; ++dt)
        #pragma unroll
        for (int kp = 0; kp < 2; ++kp)
          oc[qt][dt] = __builtin_amdgcn_mfma_f32_16x16x32_bf16(pf[qt][kp], vf[dt][kp], oc[qt][dt], 0, 0, 0);
    __builtin_amdgcn_s_setprio(0);
  }

  // ---- O -> LDS (alias flat over qs; max index 63*140+127 = 8947 < 19600) ----
  __syncthreads();
  uint16_t* Os = qs;
  #pragma unroll
  for (int qt = 0; qt < 4; ++qt)
    #pragma unroll
    for (int r = 0; r < 4; ++r) {
      int t = qt * 16 + quad * 4 + r;
      #pragma unroll
      for (int dt = 0; dt < 2; ++dt)
        Os[t * OS_STR + h * 32 + dt * 16 + lanelow] = bf16of(oc[qt][dt][r]);
    }
  __syncthreads();

  // ---- proj: rc = O @ Wo^T, this wave computes cols h*32..h*32+31 ----
  f32x4 rc[4][2];
  #pragma unroll
  for (int qt = 0; qt < 4; ++qt)
    #pragma unroll
    for (int dt = 0; dt < 2; ++dt) rc[qt][dt] = (f32x4){0.f, 0.f, 0.f, 0.f};
  #pragma unroll
  for (int kp = 0; kp < 4; ++kp) {
    short8 af[4];
    #pragma unroll
    for (int qt = 0; qt < 4; ++qt)
      af[qt] = *(const short8*)&Os[(qt * 16 + lanelow) * OS_STR + kp * 32 + quad * 8];
    short8 bfr[2];
    #pragma unroll
    for (int dt = 0; dt < 2; ++dt)
      bfr[dt] = *(const short8*)(Wo + (size_t)(h * 32 + dt * 16 + lanelow) * DIM + kp * 32 + quad * 8);
    __builtin_amdgcn_s_setprio(1);
    #pragma unroll
    for (int qt = 0; qt < 4; ++qt)
      #pragma unroll
      for (int dt = 0; dt < 2; ++dt)
        rc[qt][dt] = __builtin_amdgcn_mfma_f32_16x16x32_bf16(af[qt], bfr[dt], rc[qt][dt], 0, 0, 0);
    __builtin_amdgcn_s_setprio(0);
  }

  // ---- bias + residual (prefetched) -> rc = x stream; attn-LN partials ----
  const float b0 = bo[n0], b1 = bo[n1];
  const float ga0 = lnga[n0], ga1 = lnga[n1];
  const float ea0 = lnba[n0], ea1 = lnba[n1];
  #pragma unroll
  for (int qt = 0; qt < 4; ++qt)
    #pragma unroll
    for (int r = 0; r < 4; ++r) {
      int q = qt * 16 + quad * 4 + r;
      float v0 = rc[qt][0][r] + b0 + r0a[qt][r];
      float v1 = rc[qt][1][r] + b1 + r1a[qt][r];
      rc[qt][0][r] = v0; rc[qt][1][r] = v1;
      float s = v0 + v1, sq = v0 * v0 + v1 * v1;
      s += __shfl_xor(s, 1); sq += __shfl_xor(sq, 1);
      s += __shfl_xor(s, 2); sq += __shfl_xor(sq, 2);
      s += __shfl_xor(s, 4); sq += __shfl_xor(sq, 4);
      s += __shfl_xor(s, 8); sq += __shfl_xor(sq, 8);
      if (lanelow == 0) { lnred[rr(q)][h][0] = s; lnred[rr(q)][h][1] = sq; }
    }
  __syncthreads();   // (A) lnred ready; all proj LDS reads complete -> Os region reusable

  // ---- attn-LN finalize -> normalized bf16 tile into X_lds (Os region) ----
  uint16_t* Xl = qs;
  #pragma unroll
  for (int qt = 0; qt < 4; ++qt)
    #pragma unroll
    for (int r = 0; r < 4; ++r) {
      int q = qt * 16 + quad * 4 + r;
      int ql = rr(q);
      float s  = lnred[ql][0][0] + lnred[ql][1][0] + lnred[ql][2][0] + lnred[ql][3][0];
      float sq = lnred[ql][0][1] + lnred[ql][1][1] + lnred[ql][2][1] + lnred[ql][3][1];
      float mu = s * (1.0f / 128.0f);
      float rs = rsqrtf(sq * (1.0f / 128.0f) - mu * mu + 1e-5f);
      Xl[q * OS_STR + n0] = bf16of((rc[qt][0][r] - mu) * rs * ga0 + ea0);
      Xl[q * OS_STR + n1] = bf16of((rc[qt][1][r] - mu) * rs * ga1 + ea1);
    }
  __syncthreads();   // (B) normalized tile complete

  // ---- fused MLP GEMM: mc = norm @ Wm^T (this wave: cols n0, n1) ----
  f32x4 mc[4][2];
  #pragma unroll
  for (int qt = 0; qt < 4; ++qt)
    #pragma unroll
    for (int dt = 0; dt < 2; ++dt) mc[qt][dt] = (f32x4){0.f, 0.f, 0.f, 0.f};
  #pragma unroll
  for (int kp = 0; kp < 4; ++kp) {
    short8 af2[4];
    #pragma unroll
    for (int qt = 0; qt < 4; ++qt)
      af2[qt] = *(const short8*)&Xl[(qt * 16 + lanelow) * OS_STR + kp * 32 + quad * 8];
    short8 wfr[2];
    wfr[0] = *(const short8*)(Wm + (size_t)n0 * DIM + kp * 32 + quad * 8);
    wfr[1] = *(const short8*)(Wm + (size_t)n1 * DIM + kp * 32 + quad * 8);
    __builtin_amdgcn_s_setprio(1);
    #pragma unroll
    for (int qt = 0; qt < 4; ++qt)
      #pragma unroll
      for (int dt = 0; dt < 2; ++dt)
        mc[qt][dt] = __builtin_amdgcn_mfma_f32_16x16x32_bf16(af2[qt], wfr[dt], mc[qt][dt], 0, 0, 0);
    __builtin_amdgcn_s_setprio(0);
  }
  const float bm0 = bm[n0], bm1 = bm[n1];

  if constexpr (MLP_LN) {
    // x2 = x + mlp; post-mlp LN (ln3) partials (reuse lnred)
    const float gp0 = lngp[n0], gp1 = lngp[n1];
    const float ep0 = lnbp[n0], ep1 = lnbp[n1];
    #pragma unroll
    for (int qt = 0; qt < 4; ++qt)
      #pragma unroll
      for (int r = 0; r < 4; ++r) {
        int q = qt * 16 + quad * 4 + r;
        float v0 = rc[qt][0][r] + mc[qt][0][r] + bm0;
        float v1 = rc[qt][1][r] + mc[qt][1][r] + bm1;
        rc[qt][0][r] = v0; rc[qt][1][r] = v1;
        float s = v0 + v1, sq = v0 * v0 + v1 * v1;
        s += __shfl_xor(s, 1); sq += __shfl_xor(sq, 1);
        s += __shfl_xor(s, 2); sq += __shfl_xor(sq, 2);
        s += __shfl_xor(s, 4); sq += __shfl_xor(sq, 4);
        s += __shfl_xor(s, 8); sq += __shfl_xor(sq, 8);
        if (lanelow == 0) { lnred[rr(q)][h][0] = s; lnred[rr(q)][h][1] = sq; }
      }
    __syncthreads();   // (C)
    #pragma unroll
    for (int qt = 0; qt < 4; ++qt)
      #pragma unroll
      for (int r = 0; r < 4; ++r) {
        int q = qt * 16 + quad * 4 + r;
        if (q < 49) {
          int orow = orow_a[qt][r];
          float s  = lnred[q][0][0] + lnred[q][1][0] + lnred[q][2][0] + lnred[q][3][0];
          float sq = lnred[q][0][1] + lnred[q][1][1] + lnred[q][2][1] + lnred[q][3][1];
          float mu = s * (1.0f / 128.0f);
          float rs = rsqrtf(sq * (1.0f / 128.0f) - mu * mu + 1e-5f);
          float v0 = rc[qt][0][r], v1 = rc[qt][1][r];
          Xout[(size_t)orow * DIM + n0] = v0;
          Xout[(size_t)orow * DIM + n1] = v1;
          xbout[(size_t)orow * DIM + n0] = bf16of((v0 - mu) * rs * gp0 + ep0);
          xbout[(size_t)orow * DIM + n1] = bf16of((v1 - mu) * rs * gp1 + ep1);
        }
      }
  } else {
    // final mlp: out = mc + bm (no residual per source quirk), straight to Xout
    #pragma unroll
    for (int qt = 0; qt < 4; ++qt)
      #pragma unroll
      for (int r = 0; r < 4; ++r) {
        int q = qt * 16 + quad * 4 + r;
        if (q < 49) {
          int orow = orow_a[qt][r];
          Xout[(size_t)orow * DIM + n0] = mc[qt][0][r] + bm0;
          Xout[(size_t)orow * DIM + n1] = mc[qt][1][r] + bm1;
        }
      }
  }
}

extern "C" void kernel_launch(void* const* d_in, const int* in_sizes, int n_in,
                              void* d_out, int out_size, void* d_ws, size_t ws_size,
                              hipStream_t stream) {
  const float* x0    = (const float*)d_in[0];
  const float* ln1g  = (const float*)d_in[1];
  const float* ln1b  = (const float*)d_in[2];
  const float* wqkv1 = (const float*)d_in[3];
  const float* bqkv1 = (const float*)d_in[4];
  const float* wo1   = (const float*)d_in[5];
  const float* bo1   = (const float*)d_in[6];
  const float* tbl1  = (const float*)d_in[7];
  const float* ln2g  = (const float*)d_in[8];
  const float* ln2b  = (const float*)d_in[9];
  const float* wm1   = (const float*)d_in[10];
  const float* bm1   = (const float*)d_in[11];
  const float* ln3g  = (const float*)d_in[12];
  const float* ln3b  = (const float*)d_in[13];
  const float* wqkv2 = (const float*)d_in[14];
  const float* bqkv2 = (const float*)d_in[15];
  const float* wo2   = (const float*)d_in[16];
  const float* bo2   = (const float*)d_in[17];
  const float* tbl2  = (const float*)d_in[18];
  const float* ln4g  = (const float*)d_in[19];
  const float* ln4b  = (const float*)d_in[20];
  const float* wm2   = (const float*)d_in[21];
  const float* bm2   = (const float*)d_in[22];

  char* ws = (char*)d_ws;
  size_t off = 0;
  uint16_t* xbA  = (uint16_t*)(ws + off); off += (size_t)NTOK * 128 * sizeof(uint16_t);
  uint16_t* xb2  = (uint16_t*)(ws + off); off += (size_t)NTOK * 128 * sizeof(uint16_t);
  float* biasT1  = (float*)(ws + off);    off += 16384 * sizeof(float);
  float* biasT2  = (float*)(ws + off);    off += 16384 * sizeof(float);
  uint16_t* wb   = (uint16_t*)(ws + off); off += 163840 * sizeof(uint16_t);
  if (ws_size < off) return;
  float* x1 = (float*)d_out;   // f32 stream lives in d_out

  uint16_t* wqkv1b = wb;
  uint16_t* wqkv2b = wb + 49152;
  uint16_t* wo1b   = wb + 98304;
  uint16_t* wm1b   = wb + 114688;
  uint16_t* wo2b   = wb + 131072;
  uint16_t* wm2b   = wb + 147456;

  dim3 blk(256);
  dim3 lgrid(NTOK / 4);
  dim3 agrid(4096);

  wconv_k<<<640, blk, 0, stream>>>(wqkv1, wqkv2, wo1, wm1, wo2, wm2, wb);
  bias_k<<<64, blk, 0, stream>>>(tbl1, biasT1);
  bias_k<<<64, blk, 0, stream>>>(tbl2, biasT2);

  // ln1 -> xbA (spatial layout)
  ln_k<<<lgrid, blk, 0, stream>>>(x0, ln1g, ln1b, xbA);
  // block 1: W-MSA + proj + residual + ln2 + mlp1 + residual + ln3
  attn4<0, -1, true><<<agrid, blk, 0, stream>>>(
      xbA, wqkv1b, bqkv1, biasT1, wo1b, bo1, x0, wm1b, bm1,
      ln2g, ln2b, ln3g, ln3b, x1, xb2);
  // block 2: SW-MSA + proj + residual + ln4 + mlp2 -> final output
  attn4<3, 3, false><<<agrid, blk, 0, stream>>>(
      xb2, wqkv2b, bqkv2, biasT2, wo2b, bo2, x1, wm2b, bm2,
      ln4g, ln4b, ln4g, ln4b, x1, nullptr);
}

// Round 10
// 650.566 us; speedup vs baseline: 1.3264x; 1.3264x over previous
//
#include <hip/hip_runtime.h>
#include <hip/hip_bf16.h>
#include <stdint.h>

#define PS 56
#define S_ 3136
#define DIM 128
#define NTOK 200704   // 64 * 3136

typedef __attribute__((ext_vector_type(8))) short short8;
typedef __attribute__((ext_vector_type(4))) float f32x4;

__device__ __forceinline__ uint32_t bfpack(float a, float b){
  uint32_t ua = __float_as_uint(a); ua = (ua + 0x7fffu + ((ua >> 16) & 1u)) >> 16;
  uint32_t ub = __float_as_uint(b); ub = (ub + 0x7fffu + ((ub >> 16) & 1u)) & 0xffff0000u;
  return ua | ub;
}
__device__ __forceinline__ uint16_t bf16of(float a){
  uint32_t ua = __float_as_uint(a);
  return (uint16_t)((ua + 0x7fffu + ((ua >> 16) & 1u)) >> 16);
}
// pad-row redirect: rows 49..63 are garbage-tolerant (feed only discarded outputs);
// funnel them into one sacrificial row so the LDS tile shrinks 64 -> 50 rows.
__device__ __forceinline__ int rr(int row){ return row > 48 ? 49 : row; }

__device__ __forceinline__ int win_map(int r, int shift) {
  int b = r / S_;
  int rem = r - b * S_;
  int w = rem / 49;
  int p = rem - w * 49;
  int i = p / 7, j = p - i * 7;
  int wr = w >> 3, wc = w & 7;
  int row = wr * 7 + i + shift; if (row >= PS) row -= PS;
  int col = wc * 7 + j + shift; if (col >= PS) col -= PS;
  return b * S_ + row * PS + col;
}

// ===== LN fused to bf16 (standalone, used once for ln1) =====
__global__ __launch_bounds__(256) void ln_k(const float* __restrict__ X,
                                            const float* __restrict__ g,
                                            const float* __restrict__ b,
                                            uint16_t* __restrict__ O) {
  int t = blockIdx.x * 4 + (threadIdx.x >> 6);
  int lane = threadIdx.x & 63;
  float2 v = *(const float2*)(X + (size_t)t * DIM + lane * 2);
  float s = v.x + v.y, sq = v.x * v.x + v.y * v.y;
  #pragma unroll
  for (int o = 32; o; o >>= 1) { s += __shfl_xor(s, o); sq += __shfl_xor(sq, o); }
  float mu = s * (1.0f / 128.0f);
  float rs = rsqrtf(sq * (1.0f / 128.0f) - mu * mu + 1e-5f);
  float2 gg = *(const float2*)(g + lane * 2);
  float2 bb = *(const float2*)(b + lane * 2);
  float a = (v.x - mu) * rs * gg.x + bb.x;
  float c = (v.y - mu) * rs * gg.y + bb.y;
  ((uint32_t*)O)[(size_t)t * 64 + lane] = bfpack(a, c);
}

// ===== one-shot weight conversion f32 -> bf16 =====
__global__ __launch_bounds__(256) void wconv_k(
    const float* __restrict__ w0, const float* __restrict__ w1,
    const float* __restrict__ w2, const float* __restrict__ w3,
    const float* __restrict__ w4, const float* __restrict__ w5,
    uint16_t* __restrict__ out) {
  int i = blockIdx.x * 256 + threadIdx.x;   // 0..163839
  float v;
  if      (i <  49152) v = w0[i];
  else if (i <  98304) v = w1[i -  49152];
  else if (i < 114688) v = w2[i -  98304];
  else if (i < 131072) v = w3[i - 114688];
  else if (i < 147456) v = w4[i - 131072];
  else                 v = w5[i - 147456];
  out[i] = bf16of(v);
}

// ================= bias precompute: biasT[h][k][q], mask baked =================
__global__ __launch_bounds__(256) void bias_k(const float* __restrict__ tbl, float* __restrict__ biasT) {
  int idx = blockIdx.x * 256 + threadIdx.x;   // (h<<12 | k<<6 | q)
  int h = idx >> 12;
  int k = (idx >> 6) & 63;
  int q = idx & 63;
  float v;
  if (k >= 49)      v = -1e30f;
  else if (q >= 49) v = 0.f;
  else {
    int yi = q / 7, xi = q - yi * 7;
    int yj = k / 7, xj = k - yj * 7;
    v = tbl[((yi - yj + 6) * 13 + (xi - xj + 6)) * 4 + h];
  }
  biasT[idx] = v;
}

// ===== attn4: fused qkv + QK^T + softmax + PV + Wo proj + residual + LN + MLP =====
// 50-row LDS tile (40,960 B total) -> 4 blocks/CU at natural VGPR allocation (~116,
// which permits 4 waves/SIMD). NO launch-bounds register cap (r9 lesson: the ",4"
// forced 64 VGPR -> ~700 MB scratch spills -> 4x HBM traffic, +130 µs/dispatch).
constexpr int QKV_STR = 392;
constexpr int OS_STR  = 140;   // O / X_lds tile stride (bf16), aliases qs flat

template<int IN_SHIFT, int OUT_SHIFT, bool MLP_LN>
__global__ __launch_bounds__(256) void attn4(const uint16_t* __restrict__ xbin,
                                             const uint16_t* __restrict__ Wqkv,
                                             const float* __restrict__ bqkv,
                                             const float* __restrict__ biasT,
                                             const uint16_t* __restrict__ Wo,
                                             const float* __restrict__ bo,
                                             const float* __restrict__ Rsrc,
                                             const uint16_t* __restrict__ Wm,
                                             const float* __restrict__ bm,
                                             const float* __restrict__ lnga,
                                             const float* __restrict__ lnba,
                                             const float* __restrict__ lngp,
                                             const float* __restrict__ lnbp,
                                             float* __restrict__ Xout,
                                             uint16_t* __restrict__ xbout)
{
  __shared__ __align__(16) uint16_t qs[50 * QKV_STR];   // rows 0..48 real, 49 pad-garbage
  __shared__ float lnred[50][4][2];
  const int tid = threadIdx.x;
  const int lane = tid & 63;
  const int h = tid >> 6;
  const int lanelow = lane & 15;
  const int quad = lane >> 4;
  const int base = blockIdx.x * 49;

  // ---- phase 0: qkv = xb@Wqkv^T + bqkv, straight into qs ----
  {
    short8 af[4][4];
    #pragma unroll
    for (int mt = 0; mt < 4; ++mt) {
      int tok = mt * 16 + lanelow; if (tok > 48) tok = 48;
      int src = win_map(base + tok, IN_SHIFT);
      const uint16_t* arow = xbin + (size_t)src * DIM;
      #pragma unroll
      for (int k0 = 0; k0 < 4; ++k0)
        af[mt][k0] = *(const short8*)(arow + k0 * 32 + quad * 8);
    }
    #pragma unroll
    for (int ntl = 0; ntl < 6; ++ntl) {
      int wrow = (ntl >> 1) * 128 + h * 32 + (ntl & 1) * 16 + lanelow;
      const uint16_t* wr_ = Wqkv + (size_t)wrow * DIM;
      short8 bfr[4];
      #pragma unroll
      for (int k0 = 0; k0 < 4; ++k0)
        bfr[k0] = *(const short8*)(wr_ + k0 * 32 + quad * 8);
      f32x4 a4[4];
      #pragma unroll
      for (int mt = 0; mt < 4; ++mt) a4[mt] = (f32x4){0.f, 0.f, 0.f, 0.f};
      __builtin_amdgcn_s_setprio(1);
      #pragma unroll
      for (int k0 = 0; k0 < 4; ++k0)
        #pragma unroll
        for (int mt = 0; mt < 4; ++mt)
          a4[mt] = __builtin_amdgcn_mfma_f32_16x16x32_bf16(af[mt][k0], bfr[k0], a4[mt], 0, 0, 0);
      __builtin_amdgcn_s_setprio(0);
      float bq = bqkv[wrow];
      #pragma unroll
      for (int mt = 0; mt < 4; ++mt)
        #pragma unroll
        for (int r = 0; r < 4; ++r)
          qs[rr(mt * 16 + quad * 4 + r) * QKV_STR + wrow] = bf16of(a4[mt][r] + bq);
    }
  }

  // ---- T14: prefetch residual + output-row indices ----
  const int n0 = h * 32 + lanelow, n1 = n0 + 16;
  int   orow_a[4][4];
  float r0a[4][4], r1a[4][4];
  #pragma unroll
  for (int qt = 0; qt < 4; ++qt)
    #pragma unroll
    for (int r = 0; r < 4; ++r) {
      int q = qt * 16 + quad * 4 + r;
      bool ok = (q < 49);
      int wrow = base + (ok ? q : 0);
      int orow = (OUT_SHIFT < 0) ? wrow : win_map(wrow, OUT_SHIFT);
      orow_a[qt][r] = orow;
      r0a[qt][r] = ok ? Rsrc[(size_t)orow * DIM + n0] : 0.f;
      r1a[qt][r] = ok ? Rsrc[(size_t)orow * DIM + n1] : 0.f;
    }

  // ---- S^T = K·Q^T (each wave reads only cols it wrote; barrier after reg loads) ----
  f32x4 sc[4][4];
  #pragma unroll
  for (int kt = 0; kt < 4; ++kt)
    #pragma unroll
    for (int qt = 0; qt < 4; ++qt) sc[kt][qt] = (f32x4){0.f, 0.f, 0.f, 0.f};
  {
    short8 kf[4], qf[4];
    const int kcol = 128 + h * 32 + quad * 8;
    const int qcol = h * 32 + quad * 8;
    #pragma unroll
    for (int t = 0; t < 4; ++t) {
      int tok = t * 16 + lanelow; if (tok > 48) tok = 48;
      kf[t] = *(const short8*)(qs + tok * QKV_STR + kcol);
      qf[t] = *(const short8*)(qs + tok * QKV_STR + qcol);
    }
    __syncthreads();   // all waves hold Q,K in regs; Q/K cols become dead -> P scratch
    __builtin_amdgcn_s_setprio(1);
    #pragma unroll
    for (int kt = 0; kt < 4; ++kt)
      #pragma unroll
      for (int qt = 0; qt < 4; ++qt)
        sc[kt][qt] = __builtin_amdgcn_mfma_f32_16x16x32_bf16(kf[kt], qf[qt], sc[kt][qt], 0, 0, 0);
    __builtin_amdgcn_s_setprio(0);
  }

  // ---- scale + bias + softmax over k ----
  const float* bh = biasT + h * 4096;
  #pragma unroll
  for (int kt = 0; kt < 4; ++kt)
    #pragma unroll
    for (int r = 0; r < 4; ++r) {
      const float* br = bh + (kt * 16 + quad * 4 + r) * 64 + lanelow;
      #pragma unroll
      for (int qt = 0; qt < 4; ++qt)
        sc[kt][qt][r] = fmaf(sc[kt][qt][r], 0.17677669529663689f, br[qt * 16]);
    }
  #pragma unroll
  for (int qt = 0; qt < 4; ++qt) {
    float m = sc[0][qt][0];
    #pragma unroll
    for (int kt = 0; kt < 4; ++kt)
      #pragma unroll
      for (int r = 0; r < 4; ++r) m = fmaxf(m, sc[kt][qt][r]);
    m = fmaxf(m, __shfl_xor(m, 16));
    m = fmaxf(m, __shfl_xor(m, 32));
    float s = 0.f;
    #pragma unroll
    for (int kt = 0; kt < 4; ++kt)
      #pragma unroll
      for (int r = 0; r < 4; ++r) {
        float e = __expf(sc[kt][qt][r] - m);
        sc[kt][qt][r] = e;
        s += e;
      }
    s += __shfl_xor(s, 16);
    s += __shfl_xor(s, 32);
    float inv = 1.0f / s;
    #pragma unroll
    for (int kt = 0; kt < 4; ++kt)
      #pragma unroll
      for (int r = 0; r < 4; ++r) sc[kt][qt][r] *= inv;
  }

  // ---- P (bf16) -> dead Q/K cols: P[q][k] at qs[rr(q)*STR + h*64 + k] ----
  uint16_t* pw = qs + h * 64;
  #pragma unroll
  for (int qt = 0; qt < 4; ++qt)
    #pragma unroll
    for (int kt = 0; kt < 4; ++kt) {
      uint2 pk;
      pk.x = bfpack(sc[kt][qt][0], sc[kt][qt][1]);
      pk.y = bfpack(sc[kt][qt][2], sc[kt][qt][3]);
      *(uint2*)(pw + rr(qt * 16 + lanelow) * QKV_STR + kt * 16 + quad * 4) = pk;
    }

  // ---- O = P·V ----
  f32x4 oc[4][2];
  #pragma unroll
  for (int qt = 0; qt < 4; ++qt)
    #pragma unroll
    for (int dt = 0; dt < 2; ++dt) oc[qt][dt] = (f32x4){0.f, 0.f, 0.f, 0.f};
  {
    short8 pf[4][2];
    #pragma unroll
    for (int qt = 0; qt < 4; ++qt)
      #pragma unroll
      for (int kp = 0; kp < 2; ++kp)
        pf[qt][kp] = *(const short8*)(pw + rr(qt * 16 + lanelow) * QKV_STR + kp * 32 + quad * 8);
    short8 vf[2][2];
    #pragma unroll
    for (int dt = 0; dt < 2; ++dt)
      #pragma unroll
      for (int kp = 0; kp < 2; ++kp) {
        short8 b;
        #pragma unroll
        for (int j = 0; j < 8; ++j) {
          int tok = kp * 32 + quad * 8 + j; if (tok > 48) tok = 48;
          b[j] = (short)qs[tok * QKV_STR + 256 + h * 32 + dt * 16 + lanelow];
        }
        vf[dt][kp] = b;
      }
    __builtin_amdgcn_s_setprio(1);
    #pragma unroll
    for (int qt = 0; qt < 4; ++qt)
      #pragma unroll
      for (int dt = 0; dt < 2; ++dt)
        #pragma unroll
        for (int kp = 0; kp < 2; ++kp)
          oc[qt][dt] = __builtin_amdgcn_mfma_f32_16x16x32_bf16(pf[qt][kp], vf[dt][kp], oc[qt][dt], 0, 0, 0);
    __builtin_amdgcn_s_setprio(0);
  }

  // ---- O -> LDS (alias flat over qs; max index 63*140+127 = 8947 < 19600) ----
  __syncthreads();
  uint16_t* Os = qs;
  #pragma unroll
  for (int qt = 0; qt < 4; ++qt)
    #pragma unroll
    for (int r = 0; r < 4; ++r) {
      int t = qt * 16 + quad * 4 + r;
      #pragma unroll
      for (int dt = 0; dt < 2; ++dt)
        Os[t * OS_STR + h * 32 + dt * 16 + lanelow] = bf16of(oc[qt][dt][r]);
    }
  __syncthreads();

  // ---- proj: rc = O @ Wo^T, this wave computes cols h*32..h*32+31 ----
  f32x4 rc[4][2];
  #pragma unroll
  for (int qt = 0; qt < 4; ++qt)
    #pragma unroll
    for (int dt = 0; dt < 2; ++dt) rc[qt][dt] = (f32x4){0.f, 0.f, 0.f, 0.f};
  #pragma unroll
  for (int kp = 0; kp < 4; ++kp) {
    short8 af[4];
    #pragma unroll
    for (int qt = 0; qt < 4; ++qt)
      af[qt] = *(const short8*)&Os[(qt * 16 + lanelow) * OS_STR + kp * 32 + quad * 8];
    short8 bfr[2];
    #pragma unroll
    for (int dt = 0; dt < 2; ++dt)
      bfr[dt] = *(const short8*)(Wo + (size_t)(h * 32 + dt * 16 + lanelow) * DIM + kp * 32 + quad * 8);
    __builtin_amdgcn_s_setprio(1);
    #pragma unroll
    for (int qt = 0; qt < 4; ++qt)
      #pragma unroll
      for (int dt = 0; dt < 2; ++dt)
        rc[qt][dt] = __builtin_amdgcn_mfma_f32_16x16x32_bf16(af[qt], bfr[dt], rc[qt][dt], 0, 0, 0);
    __builtin_amdgcn_s_setprio(0);
  }

  // ---- bias + residual (prefetched) -> rc = x stream; attn-LN partials ----
  const float b0 = bo[n0], b1 = bo[n1];
  const float ga0 = lnga[n0], ga1 = lnga[n1];
  const float ea0 = lnba[n0], ea1 = lnba[n1];
  #pragma unroll
  for (int qt = 0; qt < 4; ++qt)
    #pragma unroll
    for (int r = 0; r < 4; ++r) {
      int q = qt * 16 + quad * 4 + r;
      float v0 = rc[qt][0][r] + b0 + r0a[qt][r];
      float v1 = rc[qt][1][r] + b1 + r1a[qt][r];
      rc[qt][0][r] = v0; rc[qt][1][r] = v1;
      float s = v0 + v1, sq = v0 * v0 + v1 * v1;
      s += __shfl_xor(s, 1); sq += __shfl_xor(sq, 1);
      s += __shfl_xor(s, 2); sq += __shfl_xor(sq, 2);
      s += __shfl_xor(s, 4); sq += __shfl_xor(sq, 4);
      s += __shfl_xor(s, 8); sq += __shfl_xor(sq, 8);
      if (lanelow == 0) { lnred[rr(q)][h][0] = s; lnred[rr(q)][h][1] = sq; }
    }
  __syncthreads();   // (A) lnred ready; all proj LDS reads complete -> Os region reusable

  // ---- attn-LN finalize -> normalized bf16 tile into X_lds (Os region) ----
  uint16_t* Xl = qs;
  #pragma unroll
  for (int qt = 0; qt < 4; ++qt)
    #pragma unroll
    for (int r = 0; r < 4; ++r) {
      int q = qt * 16 + quad * 4 + r;
      int ql = rr(q);
      float s  = lnred[ql][0][0] + lnred[ql][1][0] + lnred[ql][2][0] + lnred[ql][3][0];
      float sq = lnred[ql][0][1] + lnred[ql][1][1] + lnred[ql][2][1] + lnred[ql][3][1];
      float mu = s * (1.0f / 128.0f);
      float rs = rsqrtf(sq * (1.0f / 128.0f) - mu * mu + 1e-5f);
      Xl[q * OS_STR + n0] = bf16of((rc[qt][0][r] - mu) * rs * ga0 + ea0);
      Xl[q * OS_STR + n1] = bf16of((rc[qt][1][r] - mu) * rs * ga1 + ea1);
    }
  __syncthreads();   // (B) normalized tile complete

  // ---- fused MLP GEMM: mc = norm @ Wm^T (this wave: cols n0, n1) ----
  f32x4 mc[4][2];
  #pragma unroll
  for (int qt = 0; qt < 4; ++qt)
    #pragma unroll
    for (int dt = 0; dt < 2; ++dt) mc[qt][dt] = (f32x4){0.f, 0.f, 0.f, 0.f};
  #pragma unroll
  for (int kp = 0; kp < 4; ++kp) {
    short8 af2[4];
    #pragma unroll
    for (int qt = 0; qt < 4; ++qt)
      af2[qt] = *(const short8*)&Xl[(qt * 16 + lanelow) * OS_STR + kp * 32 + quad * 8];
    short8 wfr[2];
    wfr[0] = *(const short8*)(Wm + (size_t)n0 * DIM + kp * 32 + quad * 8);
    wfr[1] = *(const short8*)(Wm + (size_t)n1 * DIM + kp * 32 + quad * 8);
    __builtin_amdgcn_s_setprio(1);
    #pragma unroll
    for (int qt = 0; qt < 4; ++qt)
      #pragma unroll
      for (int dt = 0; dt < 2; ++dt)
        mc[qt][dt] = __builtin_amdgcn_mfma_f32_16x16x32_bf16(af2[qt], wfr[dt], mc[qt][dt], 0, 0, 0);
    __builtin_amdgcn_s_setprio(0);
  }
  const float bm0 = bm[n0], bm1 = bm[n1];

  if constexpr (MLP_LN) {
    // x2 = x + mlp; post-mlp LN (ln3) partials (reuse lnred)
    const float gp0 = lngp[n0], gp1 = lngp[n1];
    const float ep0 = lnbp[n0], ep1 = lnbp[n1];
    #pragma unroll
    for (int qt = 0; qt < 4; ++qt)
      #pragma unroll
      for (int r = 0; r < 4; ++r) {
        int q = qt * 16 + quad * 4 + r;
        float v0 = rc[qt][0][r] + mc[qt][0][r] + bm0;
        float v1 = rc[qt][1][r] + mc[qt][1][r] + bm1;
        rc[qt][0][r] = v0; rc[qt][1][r] = v1;
        float s = v0 + v1, sq = v0 * v0 + v1 * v1;
        s += __shfl_xor(s, 1); sq += __shfl_xor(sq, 1);
        s += __shfl_xor(s, 2); sq += __shfl_xor(sq, 2);
        s += __shfl_xor(s, 4); sq += __shfl_xor(sq, 4);
        s += __shfl_xor(s, 8); sq += __shfl_xor(sq, 8);
        if (lanelow == 0) { lnred[rr(q)][h][0] = s; lnred[rr(q)][h][1] = sq; }
      }
    __syncthreads();   // (C)
    #pragma unroll
    for (int qt = 0; qt < 4; ++qt)
      #pragma unroll
      for (int r = 0; r < 4; ++r) {
        int q = qt * 16 + quad * 4 + r;
        if (q < 49) {
          int orow = orow_a[qt][r];
          float s  = lnred[q][0][0] + lnred[q][1][0] + lnred[q][2][0] + lnred[q][3][0];
          float sq = lnred[q][0][1] + lnred[q][1][1] + lnred[q][2][1] + lnred[q][3][1];
          float mu = s * (1.0f / 128.0f);
          float rs = rsqrtf(sq * (1.0f / 128.0f) - mu * mu + 1e-5f);
          float v0 = rc[qt][0][r], v1 = rc[qt][1][r];
          Xout[(size_t)orow * DIM + n0] = v0;
          Xout[(size_t)orow * DIM + n1] = v1;
          xbout[(size_t)orow * DIM + n0] = bf16of((v0 - mu) * rs * gp0 + ep0);
          xbout[(size_t)orow * DIM + n1] = bf16of((v1 - mu) * rs * gp1 + ep1);
        }
      }
  } else {
    // final mlp: out = mc + bm (no residual per source quirk), straight to Xout
    #pragma unroll
    for (int qt = 0; qt < 4; ++qt)
      #pragma unroll
      for (int r = 0; r < 4; ++r) {
        int q = qt * 16 + quad * 4 + r;
        if (q < 49) {
          int orow = orow_a[qt][r];
          Xout[(size_t)orow * DIM + n0] = mc[qt][0][r] + bm0;
          Xout[(size_t)orow * DIM + n1] = mc[qt][1][r] + bm1;
        }
      }
  }
}

extern "C" void kernel_launch(void* const* d_in, const int* in_sizes, int n_in,
                              void* d_out, int out_size, void* d_ws, size_t ws_size,
                              hipStream_t stream) {
  const float* x0    = (const float*)d_in[0];
  const float* ln1g  = (const float*)d_in[1];
  const float* ln1b  = (const float*)d_in[2];
  const float* wqkv1 = (const float*)d_in[3];
  const float* bqkv1 = (const float*)d_in[4];
  const float* wo1   = (const float*)d_in[5];
  const float* bo1   = (const float*)d_in[6];
  const float* tbl1  = (const float*)d_in[7];
  const float* ln2g  = (const float*)d_in[8];
  const float* ln2b  = (const float*)d_in[9];
  const float* wm1   = (const float*)d_in[10];
  const float* bm1   = (const float*)d_in[11];
  const float* ln3g  = (const float*)d_in[12];
  const float* ln3b  = (const float*)d_in[13];
  const float* wqkv2 = (const float*)d_in[14];
  const float* bqkv2 = (const float*)d_in[15];
  const float* wo2   = (const float*)d_in[16];
  const float* bo2   = (const float*)d_in[17];
  const float* tbl2  = (const float*)d_in[18];
  const float* ln4g  = (const float*)d_in[19];
  const float* ln4b  = (const float*)d_in[20];
  const float* wm2   = (const float*)d_in[21];
  const float* bm2   = (const float*)d_in[22];

  char* ws = (char*)d_ws;
  size_t off = 0;
  uint16_t* xbA  = (uint16_t*)(ws + off); off += (size_t)NTOK * 128 * sizeof(uint16_t);
  uint16_t* xb2  = (uint16_t*)(ws + off); off += (size_t)NTOK * 128 * sizeof(uint16_t);
  float* biasT1  = (float*)(ws + off);    off += 16384 * sizeof(float);
  float* biasT2  = (float*)(ws + off);    off += 16384 * sizeof(float);
  uint16_t* wb   = (uint16_t*)(ws + off); off += 163840 * sizeof(uint16_t);
  if (ws_size < off) return;
  float* x1 = (float*)d_out;   // f32 stream lives in d_out

  uint16_t* wqkv1b = wb;
  uint16_t* wqkv2b = wb + 49152;
  uint16_t* wo1b   = wb + 98304;
  uint16_t* wm1b   = wb + 114688;
  uint16_t* wo2b   = wb + 131072;
  uint16_t* wm2b   = wb + 147456;

  dim3 blk(256);
  dim3 lgrid(NTOK / 4);
  dim3 agrid(4096);

  wconv_k<<<640, blk, 0, stream>>>(wqkv1, wqkv2, wo1, wm1, wo2, wm2, wb);
  bias_k<<<64, blk, 0, stream>>>(tbl1, biasT1);
  bias_k<<<64, blk, 0, stream>>>(tbl2, biasT2);

  // ln1 -> xbA (spatial layout)
  ln_k<<<lgrid, blk, 0, stream>>>(x0, ln1g, ln1b, xbA);
  // block 1: W-MSA + proj + residual + ln2 + mlp1 + residual + ln3
  attn4<0, -1, true><<<agrid, blk, 0, stream>>>(
      xbA, wqkv1b, bqkv1, biasT1, wo1b, bo1, x0, wm1b, bm1,
      ln2g, ln2b, ln3g, ln3b, x1, xb2);
  // block 2: SW-MSA + proj + residual + ln4 + mlp2 -> final output
  attn4<3, 3, false><<<agrid, blk, 0, stream>>>(
      xb2, wqkv2b, bqkv2, biasT2, wo2b, bo2, x1, wm2b, bm2,
      ln4g, ln4b, ln4g, ln4b, x1, nullptr);
}